// Round 1
// baseline (2303.809 us; speedup 1.0000x reference)
//
#include <hip/hip_runtime.h>

// ConvLstm (B=64, S=256, H=1024, fp32 in/out) — fused persistent kernel, round 7.
//
// Round-6 post-mortem (counters): MfmaUtil 5.9%, VALUBusy 8.1%, HBM 3.5% at
// 7.3 us/step => latency/serialization bound, not bandwidth/compute bound.
// Dominant cost: per-step h-exchange did 8 MiB of sc0sc1 L1/L2-BYPASS reads
// (every WG re-read its cluster's 32 KiB h slice from the LLC, 64x duplicated,
// no L2 multicast possible on the bypass path) plus 3 serialized coherence
// round trips (h-store ack -> barrier atomic -> poll), with 64 same-address
// atomic RMWs serializing per cluster per step.
//
// Round-7 changes:
//  1. h-exchange through `out` itself (out[b][t][ch] == h_t — addresses are
//     step-unique). Producers store h ONCE, write-through (sc0 sc1) so it is
//     at the LLC before signaling; consumers use PLAIN CACHED loads of
//     out[b][t-1][:]. Safe because each line is written exactly once per
//     dispatch and first touched (read) only after the flag => no L1/L2 can
//     hold a stale copy (dispatch-boundary invalidate covers graph replays).
//     The per-XCD L2 now multicasts each cluster slice to its local WGs.
//     fp16 hbuf ping-pong deleted; fp32->fp16 cvt moved to the consumer
//     (same RNE conversion => bit-identical results).
//  2. Barrier: per-cluster 64-entry FLAG ARRAY (plain sc0 sc1 dword stores,
//     value = step+1) instead of one atomic counter => no RMW serialization.
//     Wave 0 polls all 64 flags as one coalesced 256 B wave-load + __all.
//  3. h-store ack (vmcnt(0)) deferred under the x-side MFMA block (LDS-only),
//     hiding the write-through latency.
//  4. Cluster <-> XCD-pair swizzle (cluster = (bid&7)>>1, assuming the usual
//     bid%8 round-robin XCD dispatch; perf-only if mapping differs) so the
//     cached h/x slices localize in 2 L2s per cluster.
//
// Structure: 256 WGs x 256 threads, 1 WG/CU, co-resident (plain launch).
//   4 clusters x 64 WGs; cluster owns 16 batches; WG slot owns 16 channels x
//   4 gates; wave w owns K in [256w,256w+256). Wh/Wx fp16 fragments in VGPRs.
//   Per step: h-side 32 MFMAs/wave on the critical path; x-side 32 MFMAs for
//   step t+1 + LDS staging of x[t+2] run after the h store (hide its ack).
//
// ws layout: [0,1024) flag array: cluster c at uint index c*64 + slot.

#define S_LEN 256
#define H_DIM 1024
#define B_DIM 64

typedef _Float16 v8h __attribute__((ext_vector_type(8)));
typedef float v4f __attribute__((ext_vector_type(4)));

__device__ __forceinline__ v8h pack8h(float4 a, float4 b) {
  v8h r;
  r[0] = (_Float16)a.x; r[1] = (_Float16)a.y; r[2] = (_Float16)a.z; r[3] = (_Float16)a.w;
  r[4] = (_Float16)b.x; r[5] = (_Float16)b.y; r[6] = (_Float16)b.z; r[7] = (_Float16)b.w;
  return r;
}

__device__ __forceinline__ float fsigmoid(float x) { return 1.0f / (1.0f + __expf(-x)); }
__device__ __forceinline__ float ftanh(float x) {
  float e = __expf(2.0f * x);          // +inf for large x is fine: 2/(inf+1)=0
  return 1.0f - 2.0f / (e + 1.0f);
}

__global__ void k_init(unsigned* __restrict__ flags) {
  // zero the 256 per-slot flags; dispatch-boundary release makes them visible
  // to lstm_fused's sc0/sc1 bypass poll loads.
  flags[threadIdx.x] = 0u;
}

__global__ __launch_bounds__(256, 1) void lstm_fused(
    const float* __restrict__ x, const float* __restrict__ Wx,
    const float* __restrict__ Wh, const float* __restrict__ h0,
    const float* __restrict__ c0, const float* __restrict__ bx,
    const float* __restrict__ bh, const float* __restrict__ bgate,
    const float* __restrict__ peep, float* __restrict__ out,
    unsigned* __restrict__ flags) {
  __shared__ float pre[4][4][16][18];          // pad 18: store pattern 2-way (free)
  __shared__ _Float16 ldsx[16 * 1032];         // [batch][k] fp16, padded rows

  const int tid = threadIdx.x;
  const int wid = tid >> 6;                    // wave id = K-range owner
  const int lane = tid & 63;
  const int la = lane & 15;                    // MFMA: A-row (batch) / B-col (chan)
  const int lq = lane >> 4;
  const int bid = blockIdx.x;
  // XCD-pair cluster swizzle: blocks round-robin XCDs (bid%8); cluster c's 64
  // blocks live on XCDs {2c,2c+1} so cached h/x slices localize in 2 L2s.
  const int cluster = (bid & 7) >> 1;          // 4 clusters x 64 WGs
  const int slot = ((bid >> 3) << 1) | (bid & 1);
  const int ch0 = slot * 16;                   // this WG's channel slice
  const int b0 = cluster * 16;                 // this cluster's batch slice

  // ---- one-time: weight fragments into VGPRs (fp16 B-operand layout:
  // lane holds B[k = lq*8 + j][n = la]; MFMA kk covers k in [kk*32, kk*32+32)) ----
  v8h wh_f[4][8], wx_f[4][8];
  {
    const int col = wid * 256 + lq * 8;
#pragma unroll
    for (int g = 0; g < 4; ++g) {
#pragma unroll
      for (int kk = 0; kk < 8; ++kk) {
        const float* ph = Wh + (size_t)(g * 1024 + ch0 + la) * 1024 + col + kk * 32;
        wh_f[g][kk] = pack8h(*(const float4*)ph, *(const float4*)(ph + 4));
        const float* px = Wx + (size_t)(g * 1024 + ch0 + la) * 1024 + col + kk * 32;
        wx_f[g][kk] = pack8h(*(const float4*)px, *(const float4*)(px + 4));
      }
    }
  }

  // ---- elementwise-thread constants (thread <-> (batch bl, chan nn)) ----
  const int bl = tid >> 4;
  const int nn = tid & 15;
  const int gb = b0 + bl;                      // global batch
  const int ch = ch0 + nn;                     // global channel
  float bias_c[4];
#pragma unroll
  for (int g = 0; g < 4; ++g)
    bias_c[g] = bx[g * 1024 + ch] + bh[g * 1024 + ch] + bgate[g * 1024 + ch];
  const float pI = peep[ch], pF = peep[1024 + ch], pO = peep[2048 + ch];
  float c_st = c0[gb * 1024 + ch];             // cell state lives in a register

  auto stage = [&](int ts) {                   // x[:, ts, :] (cluster batches) -> LDS fp16
#pragma unroll
    for (int j = 0; j < 8; ++j) {
      int cid = tid + j * 256;                 // 2048 chunks of 8 floats
      int row = cid >> 7, c8 = cid & 127;
      const float* px = x + (size_t)(b0 + row) * (S_LEN * H_DIM) + (size_t)ts * H_DIM + c8 * 8;
      *(v8h*)(&ldsx[row * 1032 + c8 * 8]) = pack8h(*(const float4*)px, *(const float4*)(px + 4));
    }
  };
  const v4f vzero = {0.f, 0.f, 0.f, 0.f};
  v4f acc[4];
  auto xmfma = [&]() {                         // 32 x-side MFMAs from ldsx
#pragma unroll
    for (int kk = 0; kk < 8; ++kk) {
      v8h ax = *(const v8h*)(&ldsx[la * 1032 + wid * 256 + kk * 32 + lq * 8]);
#pragma unroll
      for (int g = 0; g < 4; ++g)
        acc[g] = __builtin_amdgcn_mfma_f32_16x16x32_f16(ax, wx_f[g][kk], acc[g], 0, 0, 0);
    }
  };

  // ---- prologue: x-partials for step 0, then stage x[1] ----
  stage(0);
  __syncthreads();
#pragma unroll
  for (int g = 0; g < 4; ++g) acc[g] = vzero;
  xmfma();
  __syncthreads();                             // everyone done reading x[0]
  stage(1);

  unsigned* fbase = flags + cluster * 64;      // this cluster's 64 flags (256 B)

  for (int t = 0; t < S_LEN; ++t) {
    // acc holds x-side partials for step t
    if (t > 0) {
      // wave 0: poll all 64 slot flags (one coalesced 256 B wave-load) at the
      // coherence point (sc0 sc1 bypass) until every slot signed off step t-1.
      if (wid == 0) {
        unsigned* fp = fbase + lane;
        const unsigned tgt = (unsigned)t;
        for (;;) {
          unsigned v;
          asm volatile(
              "global_load_dword %0, %[p], off sc0 sc1\n\t"
              "s_waitcnt vmcnt(0)"
              : "=v"(v) : [p] "v"(fp) : "memory");
          if (__all((int)(v >= tgt))) break;
          __builtin_amdgcn_s_sleep(1);
        }
      }
      __syncthreads();
    }

    // h_{t-1} A-fragments: PLAIN CACHED fp32 loads from out[b][t-1][:]
    // (h0 for t=0). Addresses are step-unique and first-touched only after
    // the flag => no cache can be stale; per-XCD L2 multicasts the slice.
    {
      const float* hrow = (t == 0)
          ? (h0 + (size_t)(b0 + la) * H_DIM + wid * 256 + lq * 8)
          : (out + ((size_t)(b0 + la) * S_LEN + (t - 1)) * H_DIM + wid * 256 + lq * 8);
      float4 hf0[8], hf1[8];
#pragma unroll
      for (int kk = 0; kk < 8; ++kk) {
        hf0[kk] = *(const float4*)(hrow + kk * 32);
        hf1[kk] = *(const float4*)(hrow + kk * 32 + 4);
      }
#pragma unroll
      for (int kk = 0; kk < 8; ++kk) {
        v8h ah = pack8h(hf0[kk], hf1[kk]);     // same RNE cvt as before => bit-identical
#pragma unroll
        for (int g = 0; g < 4; ++g)
          acc[g] = __builtin_amdgcn_mfma_f32_16x16x32_f16(ah, wh_f[g][kk], acc[g], 0, 0, 0);
      }
    }

    // publish wave partials: D layout col=lane&15, row=(lane>>4)*4+reg
#pragma unroll
    for (int g = 0; g < 4; ++g)
#pragma unroll
      for (int r = 0; r < 4; ++r)
        pre[wid][g][lq * 4 + r][la] = acc[g][r];
    __syncthreads();

    // elementwise gates (thread = one (batch, channel))
    float s[4];
#pragma unroll
    for (int g = 0; g < 4; ++g)
      s[g] = pre[0][g][bl][nn] + pre[1][g][bl][nn] + pre[2][g][bl][nn] +
             pre[3][g][bl][nn] + bias_c[g];
    float ig = fsigmoid(s[0] + pI * c_st);
    float fg = fsigmoid(s[1] + pF * c_st);
    float cn = fg * c_st + ig + ftanh(s[2]);   // NOTE: +ig (reference quirk), not ig*tanh
    float og = fsigmoid(s[3] + pO * cn);
    float hn = og * ftanh(cn);
    c_st = cn;

    // h -> out, write-through to the coherence point (single store serves both
    // the output tensor and the h-exchange). Ack deferred under xmfma.
    {
      float* hp = out + ((size_t)gb * S_LEN + t) * H_DIM + ch;
      asm volatile(
          "global_store_dword %[p], %[d], off sc0 sc1"
          :: [p] "v"(hp), [d] "v"(hn)
          : "memory");
    }

    if (t < S_LEN - 1) {
      // off the critical path: x-partials for step t+1 (LDS+MFMA only) while
      // the h write-through drains; then wait the ack and sign off.
#pragma unroll
      for (int g = 0; g < 4; ++g) acc[g] = vzero;
      xmfma();                                 // reads ldsx == x[t+1]
      asm volatile("s_waitcnt vmcnt(0)" ::: "memory");  // this wave's h stores acked
      __syncthreads();                         // all waves' h stores acked; also
                                               // fences ldsx reads before restage
      if (tid == 0) {
        unsigned val = (unsigned)(t + 1);      // "out[:, t, :] is at the LLC"
        asm volatile(
            "global_store_dword %[p], %[d], off sc0 sc1"
            :: [p] "v"(fbase + slot), [d] "v"(val)
            : "memory");
      }
      int tn = t + 2 < S_LEN ? t + 2 : S_LEN - 1;
      stage(tn);                               // next read is after next loop-top barrier
    } else {
      asm volatile("s_waitcnt vmcnt(0)" ::: "memory");
    }
  }
}

extern "C" void kernel_launch(void* const* d_in, const int* in_sizes, int n_in,
                              void* d_out, int out_size, void* d_ws, size_t ws_size,
                              hipStream_t stream) {
  (void)in_sizes; (void)n_in; (void)out_size; (void)ws_size;
  const float* x    = (const float*)d_in[0];
  const float* h0   = (const float*)d_in[1];
  const float* c0   = (const float*)d_in[2];
  const float* Wx   = (const float*)d_in[3];
  const float* bx   = (const float*)d_in[4];
  const float* Wh   = (const float*)d_in[5];
  const float* bh   = (const float*)d_in[6];
  const float* peep = (const float*)d_in[7];
  const float* bg   = (const float*)d_in[8];
  float* out = (float*)d_out;

  unsigned* flags = (unsigned*)d_ws;

  k_init<<<1, 256, 0, stream>>>(flags);
  lstm_fused<<<256, 256, 0, stream>>>(x, Wx, Wh, h0, c0, bx, bh, bg, peep,
                                      out, flags);
}

// Round 2
// 1884.361 us; speedup vs baseline: 1.2226x; 1.2226x over previous
//
#include <hip/hip_runtime.h>

// ConvLstm (B=64, S=256, H=1024, fp32 in/out) — fused persistent kernel, round 8.
//
// Round-7 post-mortem: cached h-exchange through `out` + flag array REGRESSED
// (7.3 -> 8.7 us/step) while FETCH/WRITE dropped => the chain is serialized
// device-scope crossing LATENCY (~1-2us each), not bandwidth. Rounds 6 and 7
// both paid 3-4 dependent crossings per step (h-store ack, flag visible,
// poll, h-load) plus a 64-WG barrier.
//
// Round-8: FLAGLESS DATAFLOW — the data is the flag. One crossing per step.
//  * hbuf: depth-4 rotating fp16 buffer [4][64][1024] in ws (512 KiB).
//    Producer WG (slot s) packs its 16ch x 16batch h-slice into LDS, then 32
//    lanes push it as 16B sc0sc1 dwordx4 stores to slot t%4 (512 B total).
//  * Consumer waves POLL THE DATA: load their 8 KiB slice (same 8x dwordx4
//    pattern as round 6) and check every dword != 0x7FFF7FFF. fp16 0x7FFF is
//    NaN; real h = sig*tanh in (-1,1) and c stays finite => sentinel is
//    unreachable by data. Per-dword checks make 16B-store tearing irrelevant.
//    On success the loaded registers feed the MFMAs directly — the poll IS
//    the h-load. No barrier, no flags: WGs self-time by dataflow.
//  * Sentinel refill: each 16B chunk has a unique owner (its producer). At
//    step t (>=2) the owner rewrites its chunk of slot (t-2)%4 with sentinel.
//    Safety (depth-4): skew between any two WGs is < 2 steps (to enter step
//    t a WG consumed h_{t-1}, so every WG pushed h_{t-1}, so every WG passed
//    step t-2's consume). Hence (a) nobody still reads slot (t-2)%4 when it
//    is refilled; (b) refill(step t) -> own push to same slot (step t+2) is
//    intra-WG, ordered by the vmcnt(0) inside the step-t+1 poll; (c) a
//    consumer can never accept stale h_{t-4}: the owner's refill was ACKED
//    (poll vmcnt) before its h_{t-2} push was issued, and seeing h_{t-2}
//    is a precondition for reaching the poll of h_{t-1}.
//  * h0 (t=0) is read directly from global (cached fp32 -> cvt), c in regs.
//  * out stores are plain cached fp32 (out is never read; dispatch-end flush
//    publishes it). No store-ack on the critical path at all.
//
// Structure: 256 WGs x 256 threads, 1 WG/CU, co-resident (plain launch).
//   4 clusters x 64 WGs; cluster owns 16 batches; WG slot owns 16 channels x
//   4 gates; wave w owns K in [256w,256w+256). Wh/Wx fp16 fragments in
//   VGPRs/AGPRs. Per step: poll+32 h-MFMAs on the chain; x-side 32 MFMAs for
//   step t+1 + LDS staging of x[t+2] off the chain.
//
// ws layout: [0, 512KiB) fp16 hbuf[4][64][1024], sentinel-filled by k_init.

#define S_LEN 256
#define H_DIM 1024
#define B_DIM 64
#define SENT 0x7FFF7FFFu

typedef _Float16 v8h __attribute__((ext_vector_type(8)));
typedef float v4f __attribute__((ext_vector_type(4)));
typedef unsigned v4u __attribute__((ext_vector_type(4)));

__device__ __forceinline__ v8h pack8h(float4 a, float4 b) {
  v8h r;
  r[0] = (_Float16)a.x; r[1] = (_Float16)a.y; r[2] = (_Float16)a.z; r[3] = (_Float16)a.w;
  r[4] = (_Float16)b.x; r[5] = (_Float16)b.y; r[6] = (_Float16)b.z; r[7] = (_Float16)b.w;
  return r;
}

__device__ __forceinline__ float fsigmoid(float x) { return 1.0f / (1.0f + __expf(-x)); }
__device__ __forceinline__ float ftanh(float x) {
  float e = __expf(2.0f * x);          // +inf for large x is fine: 2/(inf+1)=0
  return 1.0f - 2.0f / (e + 1.0f);
}

__global__ void k_init(unsigned* __restrict__ hb) {
  // sentinel-fill all 4 slots (4*64*1024 fp16 = 131072 dwords); dispatch-end
  // writeback makes them visible to lstm_fused's sc0sc1 bypass loads.
  int i = blockIdx.x * 256 + threadIdx.x;
  for (int idx = i; idx < 4 * B_DIM * H_DIM / 2; idx += gridDim.x * 256)
    hb[idx] = SENT;
}

__global__ __launch_bounds__(256, 1) void lstm_fused(
    const float* __restrict__ x, const float* __restrict__ Wx,
    const float* __restrict__ Wh, const float* __restrict__ h0,
    const float* __restrict__ c0, const float* __restrict__ bx,
    const float* __restrict__ bh, const float* __restrict__ bgate,
    const float* __restrict__ peep, float* __restrict__ out,
    _Float16* __restrict__ hbuf) {
  __shared__ float pre[4][4][16][18];          // pad 18: store pattern 2-way (free)
  __shared__ _Float16 ldsx[16 * 1032];         // [batch][k] fp16, padded rows
  __shared__ _Float16 hstage[16][16];          // gate-phase h staging for repack

  const int tid = threadIdx.x;
  const int wid = tid >> 6;                    // wave id = K-range owner
  const int lane = tid & 63;
  const int la = lane & 15;                    // MFMA: A-row (batch) / B-col (chan)
  const int lq = lane >> 4;
  const int cluster = blockIdx.x >> 6;         // 4 clusters x 64 WGs (round-6 map)
  const int slot = blockIdx.x & 63;
  const int ch0 = slot * 16;                   // this WG's channel slice
  const int b0 = cluster * 16;                 // this cluster's batch slice

  // ---- one-time: weight fragments into VGPRs (fp16 B-operand layout:
  // lane holds B[k = lq*8 + j][n = la]; MFMA kk covers k in [kk*32, kk*32+32)) ----
  v8h wh_f[4][8], wx_f[4][8];
  {
    const int col = wid * 256 + lq * 8;
#pragma unroll
    for (int g = 0; g < 4; ++g) {
#pragma unroll
      for (int kk = 0; kk < 8; ++kk) {
        const float* ph = Wh + (size_t)(g * 1024 + ch0 + la) * 1024 + col + kk * 32;
        wh_f[g][kk] = pack8h(*(const float4*)ph, *(const float4*)(ph + 4));
        const float* px = Wx + (size_t)(g * 1024 + ch0 + la) * 1024 + col + kk * 32;
        wx_f[g][kk] = pack8h(*(const float4*)px, *(const float4*)(px + 4));
      }
    }
  }

  // ---- elementwise-thread constants (thread <-> (batch bl, chan nn)) ----
  const int bl = tid >> 4;
  const int nn = tid & 15;
  const int gb = b0 + bl;                      // global batch
  const int ch = ch0 + nn;                     // global channel
  float bias_c[4];
#pragma unroll
  for (int g = 0; g < 4; ++g)
    bias_c[g] = bx[g * 1024 + ch] + bh[g * 1024 + ch] + bgate[g * 1024 + ch];
  const float pI = peep[ch], pF = peep[1024 + ch], pO = peep[2048 + ch];
  float c_st = c0[gb * 1024 + ch];             // cell state lives in a register

  auto stage = [&](int ts) {                   // x[:, ts, :] (cluster batches) -> LDS fp16
#pragma unroll
    for (int j = 0; j < 8; ++j) {
      int cid = tid + j * 256;                 // 2048 chunks of 8 floats
      int row = cid >> 7, c8 = cid & 127;
      const float* px = x + (size_t)(b0 + row) * (S_LEN * H_DIM) + (size_t)ts * H_DIM + c8 * 8;
      *(v8h*)(&ldsx[row * 1032 + c8 * 8]) = pack8h(*(const float4*)px, *(const float4*)(px + 4));
    }
  };
  const v4f vzero = {0.f, 0.f, 0.f, 0.f};
  v4f acc[4];
  auto xmfma = [&]() {                         // 32 x-side MFMAs from ldsx
#pragma unroll
    for (int kk = 0; kk < 8; ++kk) {
      v8h ax = *(const v8h*)(&ldsx[la * 1032 + wid * 256 + kk * 32 + lq * 8]);
#pragma unroll
      for (int g = 0; g < 4; ++g)
        acc[g] = __builtin_amdgcn_mfma_f32_16x16x32_f16(ax, wx_f[g][kk], acc[g], 0, 0, 0);
    }
  };

  // ---- prologue: x-partials for step 0, then stage x[1] ----
  stage(0);
  __syncthreads();
#pragma unroll
  for (int g = 0; g < 4; ++g) acc[g] = vzero;
  xmfma();
  __syncthreads();                             // everyone done reading x[0]
  stage(1);

  for (int t = 0; t < S_LEN; ++t) {
    // acc holds x-side partials for step t. Get h_{t-1} A-fragments.
    v8h ah[8];
    if (t == 0) {
      const float* hrow = h0 + (size_t)(b0 + la) * H_DIM + wid * 256 + lq * 8;
#pragma unroll
      for (int kk = 0; kk < 8; ++kk)
        ah[kk] = pack8h(*(const float4*)(hrow + kk * 32),
                        *(const float4*)(hrow + kk * 32 + 4));
    } else {
      // poll the data: reload this wave's 8 KiB slice of slot (t-1)%4 until
      // no dword is the sentinel. sc0sc1 bypass (cached lines would never
      // update). The successful load IS the h operand — one crossing total.
      const _Float16* hb = hbuf + ((t - 1) & 3) * (B_DIM * H_DIM) +
                           (size_t)(b0 + la) * H_DIM + wid * 256 + lq * 8;
      v4u u0, u1, u2, u3, u4, u5, u6, u7;
      for (;;) {
        asm volatile(
            "global_load_dwordx4 %0, %[p], off sc0 sc1\n\t"
            "global_load_dwordx4 %1, %[p], off offset:64 sc0 sc1\n\t"
            "global_load_dwordx4 %2, %[p], off offset:128 sc0 sc1\n\t"
            "global_load_dwordx4 %3, %[p], off offset:192 sc0 sc1\n\t"
            "global_load_dwordx4 %4, %[p], off offset:256 sc0 sc1\n\t"
            "global_load_dwordx4 %5, %[p], off offset:320 sc0 sc1\n\t"
            "global_load_dwordx4 %6, %[p], off offset:384 sc0 sc1\n\t"
            "global_load_dwordx4 %7, %[p], off offset:448 sc0 sc1\n\t"
            "s_waitcnt vmcnt(0)"
            : "=&v"(u0), "=&v"(u1), "=&v"(u2), "=&v"(u3),
              "=&v"(u4), "=&v"(u5), "=&v"(u6), "=&v"(u7)
            : [p] "v"(hb)
            : "memory");
        int ok = (u0[0] != SENT) & (u0[1] != SENT) & (u0[2] != SENT) & (u0[3] != SENT) &
                 (u1[0] != SENT) & (u1[1] != SENT) & (u1[2] != SENT) & (u1[3] != SENT) &
                 (u2[0] != SENT) & (u2[1] != SENT) & (u2[2] != SENT) & (u2[3] != SENT) &
                 (u3[0] != SENT) & (u3[1] != SENT) & (u3[2] != SENT) & (u3[3] != SENT) &
                 (u4[0] != SENT) & (u4[1] != SENT) & (u4[2] != SENT) & (u4[3] != SENT) &
                 (u5[0] != SENT) & (u5[1] != SENT) & (u5[2] != SENT) & (u5[3] != SENT) &
                 (u6[0] != SENT) & (u6[1] != SENT) & (u6[2] != SENT) & (u6[3] != SENT) &
                 (u7[0] != SENT) & (u7[1] != SENT) & (u7[2] != SENT) & (u7[3] != SENT);
        if (__all(ok)) break;
        __builtin_amdgcn_s_sleep(2);
      }
      ah[0] = __builtin_bit_cast(v8h, u0); ah[1] = __builtin_bit_cast(v8h, u1);
      ah[2] = __builtin_bit_cast(v8h, u2); ah[3] = __builtin_bit_cast(v8h, u3);
      ah[4] = __builtin_bit_cast(v8h, u4); ah[5] = __builtin_bit_cast(v8h, u5);
      ah[6] = __builtin_bit_cast(v8h, u6); ah[7] = __builtin_bit_cast(v8h, u7);
    }
#pragma unroll
    for (int kk = 0; kk < 8; ++kk) {
#pragma unroll
      for (int g = 0; g < 4; ++g)
        acc[g] = __builtin_amdgcn_mfma_f32_16x16x32_f16(ah[kk], wh_f[g][kk], acc[g], 0, 0, 0);
    }

    // publish wave partials: D layout col=lane&15, row=(lane>>4)*4+reg
#pragma unroll
    for (int g = 0; g < 4; ++g)
#pragma unroll
      for (int r = 0; r < 4; ++r)
        pre[wid][g][lq * 4 + r][la] = acc[g][r];
    __syncthreads();                           // sync1: pre ready

    // elementwise gates (thread = one (batch, channel))
    float s[4];
#pragma unroll
    for (int g = 0; g < 4; ++g)
      s[g] = pre[0][g][bl][nn] + pre[1][g][bl][nn] + pre[2][g][bl][nn] +
             pre[3][g][bl][nn] + bias_c[g];
    float ig = fsigmoid(s[0] + pI * c_st);
    float fg = fsigmoid(s[1] + pF * c_st);
    float cn = fg * c_st + ig + ftanh(s[2]);   // NOTE: +ig (reference quirk), not ig*tanh
    float og = fsigmoid(s[3] + pO * cn);
    float hn = og * ftanh(cn);
    c_st = cn;

    hstage[bl][nn] = (_Float16)hn;             // fp16 h for the packed push
    out[((size_t)gb * S_LEN + t) * H_DIM + t * 0 + ch] = hn;  // cached fp32 out
    __syncthreads();                           // sync2: hstage ready

    if (t < S_LEN - 1) {
      // push this WG's 512 B h-slice (32 lanes x 16B) to slot t%4, then
      // sentinel-refill our own chunk of slot (t-2)%4. Outstanding stores get
      // their vmcnt(0) inside the next step's poll — nothing waits here.
      if (tid < 32) {
        const int b = tid >> 1, half = tid & 1;
        v4u d = *(const v4u*)(&hstage[b][half * 8]);
        _Float16* hp = hbuf + (t & 3) * (B_DIM * H_DIM) +
                       (size_t)(b0 + b) * H_DIM + ch0 + half * 8;
        asm volatile("global_store_dwordx4 %[p], %[d], off sc0 sc1"
                     :: [p] "v"(hp), [d] "v"(d) : "memory");
        if (t >= 2) {
          v4u sv = {SENT, SENT, SENT, SENT};
          _Float16* rp = hbuf + ((t - 2) & 3) * (B_DIM * H_DIM) +
                         (size_t)(b0 + b) * H_DIM + ch0 + half * 8;
          asm volatile("global_store_dwordx4 %[p], %[d], off sc0 sc1"
                       :: [p] "v"(rp), [d] "v"(sv) : "memory");
        }
      }
      // off the chain: x-partials for step t+1, then stage x[t+2]
#pragma unroll
      for (int g = 0; g < 4; ++g) acc[g] = vzero;
      xmfma();                                 // reads ldsx == x[t+1]
      __syncthreads();                         // sync3: everyone done with ldsx
      int tn = t + 2 < S_LEN ? t + 2 : S_LEN - 1;
      stage(tn);                               // next read is after next sync2
    }
  }
}

extern "C" void kernel_launch(void* const* d_in, const int* in_sizes, int n_in,
                              void* d_out, int out_size, void* d_ws, size_t ws_size,
                              hipStream_t stream) {
  (void)in_sizes; (void)n_in; (void)out_size; (void)ws_size;
  const float* x    = (const float*)d_in[0];
  const float* h0   = (const float*)d_in[1];
  const float* c0   = (const float*)d_in[2];
  const float* Wx   = (const float*)d_in[3];
  const float* bx   = (const float*)d_in[4];
  const float* Wh   = (const float*)d_in[5];
  const float* bh   = (const float*)d_in[6];
  const float* peep = (const float*)d_in[7];
  const float* bg   = (const float*)d_in[8];
  float* out = (float*)d_out;

  _Float16* hbuf = (_Float16*)d_ws;            // [4][64][1024] fp16 = 512 KiB

  k_init<<<64, 256, 0, stream>>>((unsigned*)d_ws);
  lstm_fused<<<256, 256, 0, stream>>>(x, Wx, Wh, h0, c0, bx, bh, bg, peep,
                                      out, hbuf);
}

// Round 3
// 1189.651 us; speedup vs baseline: 1.9365x; 1.5840x over previous
//
#include <hip/hip_runtime.h>

// ConvLstm (B=64, S=256, H=1024, fp32 in/out) — fused persistent kernel, round 9.
//
// Round-8 post-mortem: R6 (4 crossings) 7.3 us/step, R7 (4 crossings, cached
// data) 8.7, R8 (1 crossing, fused poll=data) 7.1 => hop-count model refuted.
// VALUBusy 9.6% back-computes to ~15 poll iterations/step: consumers spin
// ~5 us before data appears. Period P ~= consumer compute (0.4 us) + delta,
// delta ~= 6 us of producer-store-issue -> remote-UC-poll-visible latency.
//
// Round-9: provably-safe structural polish; isolates delta for round 10.
//  1. Double-buffered ldsx => sync3 deleted (2 barriers/step). WAR safety:
//     stage_write(t) into buf[t&1] happens after collective sync2(t), which
//     is after every wave's tail-xmfma(t-1) reads of buf[t&1] (program order:
//     push, xmfma, stage_write precede the next poll/sync1/sync2).
//  2. stage split: 16 float4 x-loads issue right after sync1 (before gates,
//     off-chain); pack+LDS-write after the push. The poll's vmcnt(0) no
//     longer drains 64 KB of x staging at detection time.
//  3. Push (UC dwordx4, proven mechanism) immediately after sync2; out store
//     before sync2; xmfma + stage_write drain behind the push.
//  4. ldsx row stride 1042 (row bank-shift = 9 dwords, odd): 16 rows x 4 lq
//     spread exactly 2-way over 32 banks (2-way is free) => xmfma ds_read
//     conflicts eliminated.
//  5. s_sleep(1) => halved detection quantum.
// Everything else (sentinel dataflow, depth-4 rotation, refill protocol and
// its ordering proof) is identical to round 8.
//
// ws layout: [0, 512KiB) fp16 hbuf[4][64][1024], sentinel-filled by k_init.

#define S_LEN 256
#define H_DIM 1024
#define B_DIM 64
#define SENT 0x7FFF7FFFu
#define XROW 1042                              // fp16 elems per ldsx row (stride)

typedef _Float16 v8h __attribute__((ext_vector_type(8)));
typedef float v4f __attribute__((ext_vector_type(4)));
typedef unsigned v4u __attribute__((ext_vector_type(4)));

__device__ __forceinline__ v8h pack8h(float4 a, float4 b) {
  v8h r;
  r[0] = (_Float16)a.x; r[1] = (_Float16)a.y; r[2] = (_Float16)a.z; r[3] = (_Float16)a.w;
  r[4] = (_Float16)b.x; r[5] = (_Float16)b.y; r[6] = (_Float16)b.z; r[7] = (_Float16)b.w;
  return r;
}

__device__ __forceinline__ float fsigmoid(float x) { return 1.0f / (1.0f + __expf(-x)); }
__device__ __forceinline__ float ftanh(float x) {
  float e = __expf(2.0f * x);          // +inf for large x is fine: 2/(inf+1)=0
  return 1.0f - 2.0f / (e + 1.0f);
}

__global__ void k_init(unsigned* __restrict__ hb) {
  int i = blockIdx.x * 256 + threadIdx.x;
  for (int idx = i; idx < 4 * B_DIM * H_DIM / 2; idx += gridDim.x * 256)
    hb[idx] = SENT;
}

__global__ __launch_bounds__(256, 1) void lstm_fused(
    const float* __restrict__ x, const float* __restrict__ Wx,
    const float* __restrict__ Wh, const float* __restrict__ h0,
    const float* __restrict__ c0, const float* __restrict__ bx,
    const float* __restrict__ bh, const float* __restrict__ bgate,
    const float* __restrict__ peep, float* __restrict__ out,
    _Float16* __restrict__ hbuf) {
  __shared__ float pre[4][4][16][18];          // pad 18: store pattern 2-way (free)
  __shared__ _Float16 ldsx[2][16 * XROW];      // double-buffered x tiles
  __shared__ _Float16 hstage[16][16];          // gate-phase h staging for repack

  const int tid = threadIdx.x;
  const int wid = tid >> 6;                    // wave id = K-range owner
  const int lane = tid & 63;
  const int la = lane & 15;                    // MFMA: A-row (batch) / B-col (chan)
  const int lq = lane >> 4;
  const int cluster = blockIdx.x >> 6;         // 4 clusters x 64 WGs
  const int slot = blockIdx.x & 63;
  const int ch0 = slot * 16;                   // this WG's channel slice
  const int b0 = cluster * 16;                 // this cluster's batch slice

  // ---- one-time: weight fragments into VGPRs (fp16 B-operand layout:
  // lane holds B[k = lq*8 + j][n = la]; MFMA kk covers k in [kk*32, kk*32+32)) ----
  v8h wh_f[4][8], wx_f[4][8];
  {
    const int col = wid * 256 + lq * 8;
#pragma unroll
    for (int g = 0; g < 4; ++g) {
#pragma unroll
      for (int kk = 0; kk < 8; ++kk) {
        const float* ph = Wh + (size_t)(g * 1024 + ch0 + la) * 1024 + col + kk * 32;
        wh_f[g][kk] = pack8h(*(const float4*)ph, *(const float4*)(ph + 4));
        const float* px = Wx + (size_t)(g * 1024 + ch0 + la) * 1024 + col + kk * 32;
        wx_f[g][kk] = pack8h(*(const float4*)px, *(const float4*)(px + 4));
      }
    }
  }

  // ---- elementwise-thread constants (thread <-> (batch bl, chan nn)) ----
  const int bl = tid >> 4;
  const int nn = tid & 15;
  const int gb = b0 + bl;                      // global batch
  const int ch = ch0 + nn;                     // global channel
  float bias_c[4];
#pragma unroll
  for (int g = 0; g < 4; ++g)
    bias_c[g] = bx[g * 1024 + ch] + bh[g * 1024 + ch] + bgate[g * 1024 + ch];
  const float pI = peep[ch], pF = peep[1024 + ch], pO = peep[2048 + ch];
  float c_st = c0[gb * 1024 + ch];             // cell state lives in a register

  // ---- x staging, split into early load (regs) + late pack/write (LDS) ----
  float4 sreg[16];
  auto stage_load = [&](int ts) {              // issue 16 float4 loads, no wait
#pragma unroll
    for (int j = 0; j < 8; ++j) {
      int cid = tid + j * 256;                 // 2048 chunks of 8 floats
      int row = cid >> 7, c8 = cid & 127;
      const float* px = x + (size_t)(b0 + row) * (S_LEN * H_DIM) + (size_t)ts * H_DIM + c8 * 8;
      sreg[2 * j] = *(const float4*)px;
      sreg[2 * j + 1] = *(const float4*)(px + 4);
    }
  };
  auto stage_write = [&](int buf) {            // pack + LDS write (waits loads)
#pragma unroll
    for (int j = 0; j < 8; ++j) {
      int cid = tid + j * 256;
      int row = cid >> 7, c8 = cid & 127;
      *(v8h*)(&ldsx[buf][row * XROW + c8 * 8]) = pack8h(sreg[2 * j], sreg[2 * j + 1]);
    }
  };
  const v4f vzero = {0.f, 0.f, 0.f, 0.f};
  v4f acc[4];
  auto xmfma = [&](int buf) {                  // 32 x-side MFMAs from ldsx[buf]
#pragma unroll
    for (int kk = 0; kk < 8; ++kk) {
      v8h ax = *(const v8h*)(&ldsx[buf][la * XROW + wid * 256 + kk * 32 + lq * 8]);
#pragma unroll
      for (int g = 0; g < 4; ++g)
        acc[g] = __builtin_amdgcn_mfma_f32_16x16x32_f16(ax, wx_f[g][kk], acc[g], 0, 0, 0);
    }
  };

  // ---- prologue: x[0] -> buf0, x-partials for step 0, x[1] -> buf1 ----
  stage_load(0); stage_write(0);
  __syncthreads();
#pragma unroll
  for (int g = 0; g < 4; ++g) acc[g] = vzero;
  xmfma(0);
  stage_load(1); stage_write(1);               // buf1: no readers until t=0 tail

  for (int t = 0; t < S_LEN; ++t) {
    // acc holds x-side partials for step t. Get h_{t-1} A-fragments.
    v8h ah[8];
    if (t == 0) {
      const float* hrow = h0 + (size_t)(b0 + la) * H_DIM + wid * 256 + lq * 8;
#pragma unroll
      for (int kk = 0; kk < 8; ++kk)
        ah[kk] = pack8h(*(const float4*)(hrow + kk * 32),
                        *(const float4*)(hrow + kk * 32 + 4));
    } else {
      // poll the data: reload this wave's 8 KiB slice of slot (t-1)%4 until
      // no dword is the sentinel (each 16B chunk is one producer store, so
      // per-dword checks make tearing irrelevant). The successful load IS
      // the h operand.
      const _Float16* hb = hbuf + ((t - 1) & 3) * (B_DIM * H_DIM) +
                           (size_t)(b0 + la) * H_DIM + wid * 256 + lq * 8;
      v4u u0, u1, u2, u3, u4, u5, u6, u7;
      for (;;) {
        asm volatile(
            "global_load_dwordx4 %0, %[p], off sc0 sc1\n\t"
            "global_load_dwordx4 %1, %[p], off offset:64 sc0 sc1\n\t"
            "global_load_dwordx4 %2, %[p], off offset:128 sc0 sc1\n\t"
            "global_load_dwordx4 %3, %[p], off offset:192 sc0 sc1\n\t"
            "global_load_dwordx4 %4, %[p], off offset:256 sc0 sc1\n\t"
            "global_load_dwordx4 %5, %[p], off offset:320 sc0 sc1\n\t"
            "global_load_dwordx4 %6, %[p], off offset:384 sc0 sc1\n\t"
            "global_load_dwordx4 %7, %[p], off offset:448 sc0 sc1\n\t"
            "s_waitcnt vmcnt(0)"
            : "=&v"(u0), "=&v"(u1), "=&v"(u2), "=&v"(u3),
              "=&v"(u4), "=&v"(u5), "=&v"(u6), "=&v"(u7)
            : [p] "v"(hb)
            : "memory");
        int ok = (u0[0] != SENT) & (u0[1] != SENT) & (u0[2] != SENT) & (u0[3] != SENT) &
                 (u1[0] != SENT) & (u1[1] != SENT) & (u1[2] != SENT) & (u1[3] != SENT) &
                 (u2[0] != SENT) & (u2[1] != SENT) & (u2[2] != SENT) & (u2[3] != SENT) &
                 (u3[0] != SENT) & (u3[1] != SENT) & (u3[2] != SENT) & (u3[3] != SENT) &
                 (u4[0] != SENT) & (u4[1] != SENT) & (u4[2] != SENT) & (u4[3] != SENT) &
                 (u5[0] != SENT) & (u5[1] != SENT) & (u5[2] != SENT) & (u5[3] != SENT) &
                 (u6[0] != SENT) & (u6[1] != SENT) & (u6[2] != SENT) & (u6[3] != SENT) &
                 (u7[0] != SENT) & (u7[1] != SENT) & (u7[2] != SENT) & (u7[3] != SENT);
        if (__all(ok)) break;
        __builtin_amdgcn_s_sleep(1);
      }
      ah[0] = __builtin_bit_cast(v8h, u0); ah[1] = __builtin_bit_cast(v8h, u1);
      ah[2] = __builtin_bit_cast(v8h, u2); ah[3] = __builtin_bit_cast(v8h, u3);
      ah[4] = __builtin_bit_cast(v8h, u4); ah[5] = __builtin_bit_cast(v8h, u5);
      ah[6] = __builtin_bit_cast(v8h, u6); ah[7] = __builtin_bit_cast(v8h, u7);
    }
#pragma unroll
    for (int kk = 0; kk < 8; ++kk) {
#pragma unroll
      for (int g = 0; g < 4; ++g)
        acc[g] = __builtin_amdgcn_mfma_f32_16x16x32_f16(ah[kk], wh_f[g][kk], acc[g], 0, 0, 0);
    }

    // publish wave partials: D layout col=lane&15, row=(lane>>4)*4+reg
#pragma unroll
    for (int g = 0; g < 4; ++g)
#pragma unroll
      for (int r = 0; r < 4; ++r)
        pre[wid][g][lq * 4 + r][la] = acc[g][r];
    __syncthreads();                           // sync1: pre ready

    // off-chain: issue next x-tile loads NOW; they drain under gates/push.
    if (t < S_LEN - 2) stage_load(t + 2);

    // elementwise gates (thread = one (batch, channel))
    float s[4];
#pragma unroll
    for (int g = 0; g < 4; ++g)
      s[g] = pre[0][g][bl][nn] + pre[1][g][bl][nn] + pre[2][g][bl][nn] +
             pre[3][g][bl][nn] + bias_c[g];
    float ig = fsigmoid(s[0] + pI * c_st);
    float fg = fsigmoid(s[1] + pF * c_st);
    float cn = fg * c_st + ig + ftanh(s[2]);   // NOTE: +ig (reference quirk), not ig*tanh
    float og = fsigmoid(s[3] + pO * cn);
    float hn = og * ftanh(cn);
    c_st = cn;

    hstage[bl][nn] = (_Float16)hn;             // fp16 h for the packed push
    out[((size_t)gb * S_LEN + t) * H_DIM + ch] = hn;  // cached fp32 out
    __syncthreads();                           // sync2: hstage ready

    if (t < S_LEN - 1) {
      // push this WG's 512 B h-slice (32 lanes x 16B) to slot t%4, then
      // sentinel-refill our own chunk of slot (t-2)%4. Refill(t)->push(t+2)
      // same-address order is enforced by the step-t+1 poll's vmcnt(0).
      if (tid < 32) {
        const int b = tid >> 1, half = tid & 1;
        v4u d = *(const v4u*)(&hstage[b][half * 8]);
        _Float16* hp = hbuf + (t & 3) * (B_DIM * H_DIM) +
                       (size_t)(b0 + b) * H_DIM + ch0 + half * 8;
        asm volatile("global_store_dwordx4 %[p], %[d], off sc0 sc1"
                     :: [p] "v"(hp), [d] "v"(d) : "memory");
        if (t >= 2) {
          v4u sv = {SENT, SENT, SENT, SENT};
          _Float16* rp = hbuf + ((t - 2) & 3) * (B_DIM * H_DIM) +
                         (size_t)(b0 + b) * H_DIM + ch0 + half * 8;
          asm volatile("global_store_dwordx4 %[p], %[d], off sc0 sc1"
                       :: [p] "v"(rp), [d] "v"(sv) : "memory");
        }
      }
      // off the chain, behind the push: x-partials for step t+1, then the
      // LDS-write half of staging x[t+2] into buf[t&1]. WAR on buf[t&1] vs
      // tail-xmfma(t-1) readers is covered by collective sync2(t).
#pragma unroll
      for (int g = 0; g < 4; ++g) acc[g] = vzero;
      xmfma((t + 1) & 1);                      // reads buf[(t+1)&1] == x[t+1]
      if (t < S_LEN - 2) stage_write(t & 1);   // buf[t&1] <- x[t+2]
    }
  }
}

extern "C" void kernel_launch(void* const* d_in, const int* in_sizes, int n_in,
                              void* d_out, int out_size, void* d_ws, size_t ws_size,
                              hipStream_t stream) {
  (void)in_sizes; (void)n_in; (void)out_size; (void)ws_size;
  const float* x    = (const float*)d_in[0];
  const float* h0   = (const float*)d_in[1];
  const float* c0   = (const float*)d_in[2];
  const float* Wx   = (const float*)d_in[3];
  const float* bx   = (const float*)d_in[4];
  const float* Wh   = (const float*)d_in[5];
  const float* bh   = (const float*)d_in[6];
  const float* peep = (const float*)d_in[7];
  const float* bg   = (const float*)d_in[8];
  float* out = (float*)d_out;

  _Float16* hbuf = (_Float16*)d_ws;            // [4][64][1024] fp16 = 512 KiB

  k_init<<<64, 256, 0, stream>>>((unsigned*)d_ws);
  lstm_fused<<<256, 256, 0, stream>>>(x, Wx, Wh, h0, c0, bx, bh, bg, peep,
                                      out, hbuf);
}